// Round 13
// baseline (711.157 us; speedup 1.0000x reference)
//
#include <hip/hip_runtime.h>

// ---------------------------------------------------------------------------
// CustomizedMultiHeadAttention: B=4 S=2048 D=1024 H=16 DH=64
// out [B,S,D] f32  +  attn_weights [B,H,S,S] f32, concat in d_out.
// v13: == v12 (best, 539us) + gemm3_k and gemmO_k each launched 3x
//      (idempotent) as a TIMING PROBE: dur-539 ~= 2*(gemm3+gemmO).
//      Attribution round for the non-attn budget.
// ---------------------------------------------------------------------------

typedef unsigned short u16;
typedef unsigned int   u32;
typedef u16   u16x4  __attribute__((ext_vector_type(4)));
typedef u16   u16x8  __attribute__((ext_vector_type(8)));
typedef int   i32x4  __attribute__((ext_vector_type(4)));
typedef float f32x4  __attribute__((ext_vector_type(4)));
typedef __bf16 bf16x8 __attribute__((ext_vector_type(8)));

#define GLDS16(gp, lp)                                                         \
  __builtin_amdgcn_global_load_lds(                                            \
      (const __attribute__((address_space(1))) void*)(gp),                     \
      (__attribute__((address_space(3))) void*)(lp), 16, 0, 0)

__device__ __forceinline__ u16 f2bf(float x) {
  __bf16 h = (__bf16)x;
  union { __bf16 h; u16 u; } c; c.h = h; return c.u;
}
__device__ __forceinline__ float bf2f(u16 x) {
  union { u32 u; float f; } v; v.u = ((u32)x) << 16; return v.f;
}
__device__ __forceinline__ void nt_store4(float* p, f32x4 v) {
  __builtin_nontemporal_store(v, (f32x4*)p);
}

static const int Bn = 4, Sn = 2048, Dn = 1024, Hn = 16, DHn = 64;
#define MASK_NEG (-1442695.0f)   /* -1e6 * log2(e) */

// ---------------------------------------------------------------------------
// prep: blocks [0,12288) cast q,k,v -> bf16; [12288,13312) weight cast+T;
//       [13312,15360) mask all-ones flags per [64 sk x 128 sq] tile.
// ---------------------------------------------------------------------------
__global__ __launch_bounds__(256) void prep_k(
    const float* __restrict__ q, const float* __restrict__ k,
    const float* __restrict__ v, const float* __restrict__ mask,
    const float* __restrict__ w0, const float* __restrict__ w1,
    const float* __restrict__ w2, const float* __restrict__ w3,
    u16* __restrict__ qkv, u16* __restrict__ WTb, int* __restrict__ flags) {
  __shared__ __align__(16) u16 tile[64][72];
  __shared__ int ok_s;
  int bid = blockIdx.x, t = threadIdx.x;

  if (bid < 12288) {                      // ---- cast q,k,v
    int which = bid >> 12;
    size_t li = (size_t)(bid & 4095) * 256 + t;
    const float* src = which == 0 ? q : which == 1 ? k : v;
    const f32x4* p = (const f32x4*)src + li * 2;
    f32x4 a = p[0], b = p[1];
    u16x8 r;
    r[0]=f2bf(a[0]); r[1]=f2bf(a[1]); r[2]=f2bf(a[2]); r[3]=f2bf(a[3]);
    r[4]=f2bf(b[0]); r[5]=f2bf(b[1]); r[6]=f2bf(b[2]); r[7]=f2bf(b[3]);
    *((u16x8*)(qkv + (size_t)which * 8388608) + li) = r;
  } else if (bid < 13312) {               // ---- weight cast + transpose
    int i = bid - 12288;
    int z = i >> 8, rem = i & 255, bx = rem & 15, by = rem >> 4;
    const float* W = z == 0 ? w0 : z == 1 ? w1 : z == 2 ? w2 : w3;
    u16* WT = WTb + (size_t)z * 1048576;
    for (int rr = 0; rr < 4; rr++) {
      int r = rr * 16 + (t >> 4);
      int c = (t & 15) * 4;
      float4 vv = *(const float4*)(W + (size_t)(by * 64 + r) * 1024 + bx * 64 + c);
      tile[c + 0][r] = f2bf(vv.x); tile[c + 1][r] = f2bf(vv.y);
      tile[c + 2][r] = f2bf(vv.z); tile[c + 3][r] = f2bf(vv.w);
    }
    __syncthreads();
    for (int rr = 0; rr < 2; rr++) {
      int gid = rr * 256 + t;
      int r = gid >> 3, g = gid & 7;
      u16x8 vv = *(const u16x8*)&tile[r][g * 8];
      *(u16x8*)(WT + (size_t)(bx * 64 + r) * 1024 + by * 64 + g * 8) = vv;
    }
  } else {                                // ---- mask flags
    int i = bid - 13312;
    int qt = i & 15, kt = (i >> 4) & 31, b = i >> 9;
    if (t == 0) ok_s = 1;
    __syncthreads();
    const float* base = mask + ((size_t)b * Sn + qt * 128) * Sn + kt * 64;
    int r = t >> 1, c0 = (t & 1) * 32;
    const float* p = base + (size_t)r * Sn + c0;
    bool ok = true;
    for (int j = 0; j < 8; j++) {
      float4 vv = *(const float4*)(p + j * 4);
      ok = ok && (vv.x == 1.0f) && (vv.y == 1.0f) && (vv.z == 1.0f) && (vv.w == 1.0f);
    }
    if (!ok) atomicAnd(&ok_s, 0);
    __syncthreads();
    if (t == 0) flags[(b * 32 + kt) * 16 + qt] = ok_s;
  }
}

// ---------------------------------------------------------------------------
// GEMM core (v10): 128x128 tile, BK=64, 4 waves; coalesced LDS-routed
// epilogues for bf16 modes.
// ---------------------------------------------------------------------------
__device__ __forceinline__ void gemm_body(const u16* __restrict__ A,
                                          const u16* __restrict__ BT,
                                          const float* __restrict__ bias,
                                          void* __restrict__ outp, int mode,
                                          int nt, int mt, char* sm) {
  const int K = 1024;
  int m0 = mt * 128, n0 = nt * 128;
  int tid = threadIdx.x, w = tid >> 6, l = tid & 63, l15 = l & 15, l4 = l >> 4;
  int wm = w >> 1, wn = w & 1;

  size_t goff_a[4], goff_b[4];
  int lbase[4];
  for (int i = 0; i < 4; i++) {
    int gi = (w * 4 + i) * 64 + l;
    int row = gi >> 3, g = gi & 7;
    int gx = g ^ (row & 7);
    goff_a[i] = (size_t)(m0 + row) * K + gx * 8;
    goff_b[i] = (size_t)(n0 + row) * K + gx * 8;
    lbase[i] = (w * 4 + i) * 1024;
  }

  f32x4 acc[4][4] = {};
  for (int t = 0; t < 16; t++) {
    int k0 = t * 64;
    for (int i = 0; i < 4; i++) {
      GLDS16(A + goff_a[i] + k0, sm + lbase[i]);
      GLDS16(BT + goff_b[i] + k0, sm + 16384 + lbase[i]);
    }
    __syncthreads();
#pragma unroll
    for (int kk = 0; kk < 2; kk++) {
      int kb = kk * 64 + l4 * 16;
      bf16x8 af[4], bf[4];
#pragma unroll
      for (int mi = 0; mi < 4; mi++) {
        int row = wm * 64 + mi * 16 + l15;
        af[mi] = *(const bf16x8*)(sm + row * 128 + (kb ^ ((row & 7) << 4)));
      }
#pragma unroll
      for (int nj = 0; nj < 4; nj++) {
        int row = wn * 64 + nj * 16 + l15;
        bf[nj] = *(const bf16x8*)(sm + 16384 + row * 128 + (kb ^ ((row & 7) << 4)));
      }
#pragma unroll
      for (int mi = 0; mi < 4; mi++)
#pragma unroll
        for (int nj = 0; nj < 4; nj++)
          acc[mi][nj] = __builtin_amdgcn_mfma_f32_16x16x32_bf16(af[mi], bf[nj], acc[mi][nj], 0, 0, 0);
    }
    __syncthreads();
  }

  if (mode == 3) {
    float* out = (float*)outp;
#pragma unroll
    for (int mi = 0; mi < 4; mi++)
#pragma unroll
      for (int nj = 0; nj < 4; nj++)
#pragma unroll
        for (int r = 0; r < 4; r++) {
          int mg = m0 + wm * 64 + mi * 16 + l4 * 4 + r;
          int ng = n0 + wn * 64 + nj * 16 + l15;
          __builtin_nontemporal_store(acc[mi][nj][r] + bias[ng],
                                      out + (size_t)mg * 1024 + ng);
        }
  } else if (mode == 2) {
    u16* vt = (u16*)outp;
#pragma unroll
    for (int mi = 0; mi < 4; mi++)
#pragma unroll
      for (int nj = 0; nj < 4; nj++) {
        int col = wn * 64 + nj * 16 + l15;
        int rowb = wm * 64 + mi * 16 + l4 * 4;
        float bs = bias[n0 + col];
        u16x4 pk;
#pragma unroll
        for (int r = 0; r < 4; r++) pk[r] = f2bf(acc[mi][nj][r] + bs);
        *(u16x4*)(sm + col * 256 + (((rowb >> 3) * 16) ^ ((col & 7) << 4)) + (rowb & 7) * 2) = pk;
      }
    __syncthreads();
#pragma unroll
    for (int pass = 0; pass < 8; pass++) {
      int idx = pass * 256 + tid;
      int g = idx & 15, col = idx >> 4;
      i32x4 v = *(const i32x4*)(sm + col * 256 + ((g * 16) ^ ((col & 7) << 4)));
      int ng = n0 + col, h = ng >> 6, d = ng & 63;
      int mgb = m0 + g * 8, b = mgb >> 11, s = mgb & 2047;
      *(i32x4*)(vt + ((size_t)(b * Hn + h) * DHn + d) * Sn + s) = v;
    }
  } else {
    u16* oh = (u16*)outp;
    float sc = (mode == 0) ? 0.18033688f : 1.0f;   // 0.125 * log2(e)
#pragma unroll
    for (int mi = 0; mi < 4; mi++)
#pragma unroll
      for (int nj = 0; nj < 4; nj++) {
        int col = wn * 64 + nj * 16 + l15;
        float bs = bias[n0 + col];
#pragma unroll
        for (int r = 0; r < 4; r++) {
          int row = wm * 64 + mi * 16 + l4 * 4 + r;
          *(u16*)(sm + row * 256 + (((col >> 3) * 16) ^ ((row & 7) << 4)) + (col & 7) * 2) =
              f2bf((acc[mi][nj][r] + bs) * sc);
        }
      }
    __syncthreads();
#pragma unroll
    for (int pass = 0; pass < 8; pass++) {
      int idx = pass * 256 + tid;
      int g = idx & 7, half = (idx >> 3) & 1, row = idx >> 4;
      i32x4 v = *(const i32x4*)(sm + row * 256 + (((half * 8 + g) * 16) ^ ((row & 7) << 4)));
      int hg = (n0 >> 6) + half;
      int mg = m0 + row, b = mg >> 11, s = mg & 2047;
      *(i32x4*)(oh + ((size_t)(b * Hn + hg) * Sn + s) * DHn + g * 8) = v;
    }
  }
}

__global__ __launch_bounds__(256) void gemmO_k(const u16* __restrict__ A,
                                               const u16* __restrict__ BT,
                                               const float* __restrict__ bias,
                                               float* __restrict__ outp) {
  __shared__ __align__(16) char sm[32768];
  int hw = blockIdx.x;
  int lg = (hw & 7) * 64 + (hw >> 3);
  int nt = lg & 7, mt = lg >> 3;
  gemm_body(A, BT, bias, (void*)outp, 3, nt, mt, sm);
}

__global__ __launch_bounds__(256) void gemm3_k(const u16* __restrict__ Ab,
                                               const u16* __restrict__ BTb,
                                               const float* __restrict__ b0,
                                               const float* __restrict__ b1,
                                               const float* __restrict__ b2,
                                               u16* __restrict__ outb) {
  __shared__ __align__(16) char sm[32768];
  int hw = blockIdx.x;
  int lg = (hw & 7) * 192 + (hw >> 3);
  int z = lg >> 9, r = lg & 511;
  int nt = r & 7, mt = r >> 3;
  const u16* A = Ab + (size_t)z * 8388608;
  const u16* BT = BTb + (size_t)z * 1048576;
  const float* bias = z == 0 ? b0 : z == 1 ? b1 : b2;
  u16* out = outb + (size_t)z * 8388608;
  gemm_body(A, BT, bias, (void*)out, z, nt, mt, sm);
}

// ---------------------------------------------------------------------------
// Merged attention (v12). 1D grid 1024, XCD-chunked. 4 waves, 48KB.
// Phase A: c = log2(sum exp2(s')), KBLK=128, K dbuf in [0,32K).
// Phase B: KBLK=64, K/V dbuf, wave-private P; attn stored from the bf16 P
// tile in LDS, transposed: each instr = 4 rows x 256B contiguous (NT).
// LDS: K0 8K | K1 8K | V0 8K | V1 8K | P 16K = 48KB.
// ---------------------------------------------------------------------------
#define K0_OFF 0
#define K1_OFF 8192
#define V0_OFF 16384
#define V1_OFF 24576
#define P_OFF  32768

__global__ __launch_bounds__(256) void attn_k(
    const u16* __restrict__ qh, const u16* __restrict__ kh,
    const u16* __restrict__ vt, const float* __restrict__ mask,
    const int* __restrict__ flags, float* __restrict__ attn,
    u16* __restrict__ ctxc) {
  __shared__ __align__(16) char sm[49152];
  int hw = blockIdx.x;
  int lg = (hw & 7) * 128 + (hw >> 3);
  int qt = lg & 15, h = (lg >> 4) & 15, b = lg >> 8;
  int bh = b * Hn + h;
  int tid = threadIdx.x, w = tid >> 6, l = tid & 63, l15 = l & 15, l4 = l >> 4;

  const u16* Qg = qh + ((size_t)bh * Sn + qt * 128) * DHn;
  const u16* Kg = kh + (size_t)bh * Sn * DHn;
  const u16* Vg = vt + (size_t)bh * DHn * Sn;
  const float* Mg = mask + (size_t)b * Sn * Sn + (size_t)(qt * 128) * Sn;

  u32 fl = (u32)__ballot(l < 32 && flags[(b * 32 + l) * 16 + qt] != 0);

  int srowA[4], sgxA[4], sdstA[4];
  for (int i = 0; i < 4; i++) {
    int gid = i * 256 + tid, row = gid >> 3, g = gid & 7;
    srowA[i] = row; sgxA[i] = (g ^ (row & 7)) * 8; sdstA[i] = gid * 16;
  }
#define STAGE_KA(t, buf)                                                       \
  for (int i = 0; i < 4; i++)                                                  \
    GLDS16(Kg + (size_t)((t) * 128 + srowA[i]) * DHn + sgxA[i], sm + (buf) + sdstA[i]);
#define STAGE_K(t, buf)                                                        \
  for (int i = 0; i < 2; i++)                                                  \
    GLDS16(Kg + (size_t)((t) * 64 + srowA[i]) * DHn + sgxA[i], sm + (buf) + sdstA[i]);
#define STAGE_V(t, buf)                                                        \
  for (int i = 0; i < 2; i++)                                                  \
    GLDS16(Vg + (size_t)srowA[i] * Sn + (t) * 64 + sgxA[i], sm + (buf) + sdstA[i]);

  bf16x8 qf[2][2];
#pragma unroll
  for (int ni = 0; ni < 2; ni++)
#pragma unroll
    for (int kk = 0; kk < 2; kk++)
      qf[ni][kk] = *(const bf16x8*)(Qg + (size_t)(w * 32 + ni * 16 + l15) * DHn + kk * 32 + l4 * 8);

  // ---------------- phase A: lsum (no max tracking) ----------------
  float lsum[2] = {0.f, 0.f};
  STAGE_KA(0, 0);
  for (int t = 0; t < 16; t++) {
    int kcur = (t & 1) ? 16384 : 0;
    __syncthreads();
    if (t < 15) { int knxt = (t & 1) ? 0 : 16384; STAGE_KA(t + 1, knxt); }
#pragma unroll
    for (int h2 = 0; h2 < 2; h2++) {
      int kt = t * 2 + h2;
      f32x4 s[4][2] = {};
#pragma unroll
      for (int kk = 0; kk < 2; kk++) {
        int kb = kk * 64 + l4 * 16;
        bf16x8 a[4];
#pragma unroll
        for (int mi = 0; mi < 4; mi++) {
          int row = h2 * 64 + mi * 16 + l15;
          a[mi] = *(const bf16x8*)(sm + kcur + row * 128 + (kb ^ ((row & 7) << 4)));
        }
#pragma unroll
        for (int mi = 0; mi < 4; mi++)
#pragma unroll
          for (int ni = 0; ni < 2; ni++)
            s[mi][ni] = __builtin_amdgcn_mfma_f32_16x16x32_bf16(a[mi], qf[ni][kk], s[mi][ni], 0, 0, 0);
      }
      if (!((fl >> kt) & 1)) {
#pragma unroll
        for (int ni = 0; ni < 2; ni++) {
          const float* mrow = Mg + (size_t)(w * 32 + ni * 16 + l15) * Sn + kt * 64;
#pragma unroll
          for (int mi = 0; mi < 4; mi++) {
            f32x4 mv = *(const f32x4*)(mrow + mi * 16 + l4 * 4);
#pragma unroll
            for (int r = 0; r < 4; r++)
              s[mi][ni][r] = s[mi][ni][r] * mv[r] + MASK_NEG * (1.f - mv[r]);
          }
        }
      }
#pragma unroll
      for (int ni = 0; ni < 2; ni++)
#pragma unroll
        for (int mi = 0; mi < 4; mi++)
#pragma unroll
          for (int r = 0; r < 4; r++) lsum[ni] += __builtin_exp2f(s[mi][ni][r]);
    }
  }
  float cv[2];
#pragma unroll
  for (int ni = 0; ni < 2; ni++) {
    lsum[ni] += __shfl_xor(lsum[ni], 16);
    lsum[ni] += __shfl_xor(lsum[ni], 32);
    cv[ni] = __builtin_log2f(lsum[ni]);
  }

  // ---------------- phase B: P pack + transposed stores + PV ----------------
  __syncthreads();
  f32x4 ctx[4][2] = {};
  STAGE_K(0, K0_OFF);
  STAGE_V(0, V0_OFF);
  for (int t = 0; t < 32; t++) {
    int kcur = (t & 1) ? K1_OFF : K0_OFF;
    int vcur = (t & 1) ? V1_OFF : V0_OFF;
    __syncthreads();
    if (t < 31) {
      int knxt = (t & 1) ? K0_OFF : K1_OFF;
      int vnxt = (t & 1) ? V0_OFF : V1_OFF;
      STAGE_K(t + 1, knxt);
      STAGE_V(t + 1, vnxt);
    }
    f32x4 s[4][2] = {};
#pragma unroll
    for (int kk = 0; kk < 2; kk++) {
      int kb = kk * 64 + l4 * 16;
      bf16x8 a[4];
#pragma unroll
      for (int mi = 0; mi < 4; mi++) {
        int row = mi * 16 + l15;
        a[mi] = *(const bf16x8*)(sm + kcur + row * 128 + (kb ^ ((row & 7) << 4)));
      }
#pragma unroll
      for (int mi = 0; mi < 4; mi++)
#pragma unroll
        for (int ni = 0; ni < 2; ni++)
          s[mi][ni] = __builtin_amdgcn_mfma_f32_16x16x32_bf16(a[mi], qf[ni][kk], s[mi][ni], 0, 0, 0);
    }
    if (!((fl >> t) & 1)) {
#pragma unroll
      for (int ni = 0; ni < 2; ni++) {
        const float* mrow = Mg + (size_t)(w * 32 + ni * 16 + l15) * Sn + t * 64;
#pragma unroll
        for (int mi = 0; mi < 4; mi++) {
          f32x4 mv = *(const f32x4*)(mrow + mi * 16 + l4 * 4);
#pragma unroll
          for (int r = 0; r < 4; r++)
            s[mi][ni][r] = s[mi][ni][r] * mv[r] + MASK_NEG * (1.f - mv[r]);
        }
      }
    }
    // s := exp2(s - c)  -> normalized attention weight
#pragma unroll
    for (int ni = 0; ni < 2; ni++)
#pragma unroll
      for (int mi = 0; mi < 4; mi++)
#pragma unroll
        for (int r = 0; r < 4; r++) s[mi][ni][r] = __builtin_exp2f(s[mi][ni][r] - cv[ni]);
    // P -> LDS (bf16, wave-private rows)
#pragma unroll
    for (int ni = 0; ni < 2; ni++) {
      int q = w * 32 + ni * 16 + l15;
#pragma unroll
      for (int mi = 0; mi < 4; mi++) {
        u16x4 pk;
#pragma unroll
        for (int r = 0; r < 4; r++) pk[r] = f2bf(s[mi][ni][r]);
        int kb = mi * 32 + l4 * 8;
        *(u16x4*)(sm + P_OFF + q * 128 + (kb ^ ((q & 7) << 4))) = pk;
      }
    }
    // attn store from LDS, transposed: instr j = 4 rows x 256B contiguous
#pragma unroll
    for (int j = 0; j < 8; j++) {
      int q = w * 32 + j * 4 + l4;            // own wave's rows
      u16x4 pv = *(const u16x4*)(sm + P_OFF + q * 128 + ((l15 * 8) ^ ((q & 7) << 4)));
      f32x4 o;
#pragma unroll
      for (int r = 0; r < 4; r++) o[r] = bf2f(pv[r]);
      nt_store4(attn + ((size_t)bh * Sn + qt * 128 + q) * Sn + t * 64 + l15 * 4, o);
    }
    // PV: ctx^T += Vt x P^T (bp reads own wave's P rows only)
#pragma unroll
    for (int kk = 0; kk < 2; kk++) {
      int kb = kk * 64 + l4 * 16;
      bf16x8 av[4], bp[2];
#pragma unroll
      for (int mi = 0; mi < 4; mi++) {
        int row = mi * 16 + l15;
        av[mi] = *(const bf16x8*)(sm + vcur + row * 128 + (kb ^ ((row & 7) << 4)));
      }
#pragma unroll
      for (int ni = 0; ni < 2; ni++) {
        int q = w * 32 + ni * 16 + l15;
        bp[ni] = *(const bf16x8*)(sm + P_OFF + q * 128 + (kb ^ ((q & 7) << 4)));
      }
#pragma unroll
      for (int mi = 0; mi < 4; mi++)
#pragma unroll
        for (int ni = 0; ni < 2; ni++)
          ctx[mi][ni] = __builtin_amdgcn_mfma_f32_16x16x32_bf16(av[mi], bp[ni], ctx[mi][ni], 0, 0, 0);
    }
  }

  // ctx epilogue (already normalized): bf16 pack, LDS, coalesced store
#pragma unroll
  for (int ni = 0; ni < 2; ni++) {
    int q = w * 32 + ni * 16 + l15;
#pragma unroll
    for (int mi = 0; mi < 4; mi++) {
      u16x4 ck;
#pragma unroll
      for (int r = 0; r < 4; r++) ck[r] = f2bf(ctx[mi][ni][r]);
      int db = mi * 32 + l4 * 8;
      *(u16x4*)(sm + P_OFF + q * 128 + (db ^ ((q & 7) << 4))) = ck;
    }
  }
  __syncthreads();
  {
    int q = tid >> 1, hf = tid & 1;
    u16* dst = ctxc + ((size_t)b * Sn + qt * 128 + q) * Dn + h * DHn + hf * 32;
#pragma unroll
    for (int c4 = 0; c4 < 4; c4++) {
      int db = hf * 64 + c4 * 16;
      i32x4 v = *(const i32x4*)(sm + P_OFF + q * 128 + (db ^ ((q & 7) << 4)));
      *(i32x4*)(dst + c4 * 8) = v;
    }
  }
}

// ---------------------------------------------------------------------------
extern "C" void kernel_launch(void* const* d_in, const int* in_sizes, int n_in,
                              void* d_out, int out_size, void* d_ws, size_t ws_size,
                              hipStream_t stream) {
  const float* v_f  = (const float*)d_in[0];
  const float* k_f  = (const float*)d_in[1];
  const float* q_f  = (const float*)d_in[2];
  const float* mask = (const float*)d_in[3];
  const float* wq_w = (const float*)d_in[4];
  const float* wq_b = (const float*)d_in[5];
  const float* wk_w = (const float*)d_in[6];
  const float* wk_b = (const float*)d_in[7];
  const float* wv_w = (const float*)d_in[8];
  const float* wv_b = (const float*)d_in[9];
  const float* wo_w = (const float*)d_in[10];
  const float* wo_b = (const float*)d_in[11];

  char* ws = (char*)d_ws;
  u16*   qbf  = (u16*)(ws + 0);             // q,k,v bf16 slabs (contig)
  u16*   wT   = (u16*)(ws + 50331648);      // wqT,wkT,wvT,woT (contig, 2MB ea)
  u16*   woT  = (u16*)(ws + 56623104);
  u16*   qhp  = (u16*)(ws + 58720256);      // Qh, Kh, Vt slabs (contig, 16MB ea)
  u16*   khp  = (u16*)(ws + 75497472);
  u16*   vtp  = (u16*)(ws + 92274688);
  u16*   ctxc = (u16*)(ws + 109051904);
  int*   flg  = (int*)(ws + 125829120);

  float* out  = (float*)d_out;
  float* attn = out + (size_t)Bn * Sn * Dn;

  prep_k<<<15360, 256, 0, stream>>>(q_f, k_f, v_f, mask,
                                    wq_w, wk_w, wv_w, wo_w, qbf, wT, flg);

  // TIMING PROBE: gemm3_k / gemmO_k are idempotent; run each 3x so
  // (dur - 539) / 2 ~= gemm3_us + gemmO_us.
  gemm3_k<<<1536, 256, 0, stream>>>(qbf, wT, wq_b, wk_b, wv_b, qhp);
  gemm3_k<<<1536, 256, 0, stream>>>(qbf, wT, wq_b, wk_b, wv_b, qhp);
  gemm3_k<<<1536, 256, 0, stream>>>(qbf, wT, wq_b, wk_b, wv_b, qhp);

  attn_k<<<1024, 256, 0, stream>>>(qhp, khp, vtp, mask, flg, attn, ctxc);

  gemmO_k<<<512, 256, 0, stream>>>(ctxc, woT, wo_b, out);
  gemmO_k<<<512, 256, 0, stream>>>(ctxc, woT, wo_b, out);
  gemmO_k<<<512, 256, 0, stream>>>(ctxc, woT, wo_b, out);
}

// Round 14
// 533.929 us; speedup vs baseline: 1.3319x; 1.3319x over previous
//
#include <hip/hip_runtime.h>

// ---------------------------------------------------------------------------
// CustomizedMultiHeadAttention: B=4 S=2048 D=1024 H=16 DH=64
// out [B,S,D] f32  +  attn_weights [B,H,S,S] f32, concat in d_out.
// v14: = v12 but the q/k/v f32->bf16 cast pass is ELIMINATED: gemm3 reads
//      f32 inputs directly, reg-staging A tiles (f32 load -> cvt -> ds_write
//      to the same pre-swizzled linear LDS layout); B stays global_load_lds.
//      prep shrinks to weights+flags (3072 blocks). Attn/gemmO unchanged.
// ---------------------------------------------------------------------------

typedef unsigned short u16;
typedef unsigned int   u32;
typedef u16   u16x4  __attribute__((ext_vector_type(4)));
typedef u16   u16x8  __attribute__((ext_vector_type(8)));
typedef int   i32x4  __attribute__((ext_vector_type(4)));
typedef float f32x4  __attribute__((ext_vector_type(4)));
typedef __bf16 bf16x8 __attribute__((ext_vector_type(8)));

#define GLDS16(gp, lp)                                                         \
  __builtin_amdgcn_global_load_lds(                                            \
      (const __attribute__((address_space(1))) void*)(gp),                     \
      (__attribute__((address_space(3))) void*)(lp), 16, 0, 0)

__device__ __forceinline__ u16 f2bf(float x) {
  __bf16 h = (__bf16)x;
  union { __bf16 h; u16 u; } c; c.h = h; return c.u;
}
__device__ __forceinline__ float bf2f(u16 x) {
  union { u32 u; float f; } v; v.u = ((u32)x) << 16; return v.f;
}
__device__ __forceinline__ void nt_store4(float* p, f32x4 v) {
  __builtin_nontemporal_store(v, (f32x4*)p);
}

static const int Bn = 4, Sn = 2048, Dn = 1024, Hn = 16, DHn = 64;
#define MASK_NEG (-1442695.0f)   /* -1e6 * log2(e) */

// ---------------------------------------------------------------------------
// prep: blocks [0,1024) weight cast+T; [1024,3072) mask all-ones flags.
// ---------------------------------------------------------------------------
__global__ __launch_bounds__(256) void prep_k(
    const float* __restrict__ mask,
    const float* __restrict__ w0, const float* __restrict__ w1,
    const float* __restrict__ w2, const float* __restrict__ w3,
    u16* __restrict__ WTb, int* __restrict__ flags) {
  __shared__ __align__(16) u16 tile[64][72];
  __shared__ int ok_s;
  int bid = blockIdx.x, t = threadIdx.x;

  if (bid < 1024) {                       // ---- weight cast + transpose
    int i = bid;
    int z = i >> 8, rem = i & 255, bx = rem & 15, by = rem >> 4;
    const float* W = z == 0 ? w0 : z == 1 ? w1 : z == 2 ? w2 : w3;
    u16* WT = WTb + (size_t)z * 1048576;
    for (int rr = 0; rr < 4; rr++) {
      int r = rr * 16 + (t >> 4);
      int c = (t & 15) * 4;
      float4 vv = *(const float4*)(W + (size_t)(by * 64 + r) * 1024 + bx * 64 + c);
      tile[c + 0][r] = f2bf(vv.x); tile[c + 1][r] = f2bf(vv.y);
      tile[c + 2][r] = f2bf(vv.z); tile[c + 3][r] = f2bf(vv.w);
    }
    __syncthreads();
    for (int rr = 0; rr < 2; rr++) {
      int gid = rr * 256 + t;
      int r = gid >> 3, g = gid & 7;
      u16x8 vv = *(const u16x8*)&tile[r][g * 8];
      *(u16x8*)(WT + (size_t)(bx * 64 + r) * 1024 + by * 64 + g * 8) = vv;
    }
  } else {                                // ---- mask flags
    int i = bid - 1024;
    int qt = i & 15, kt = (i >> 4) & 31, b = i >> 9;
    if (t == 0) ok_s = 1;
    __syncthreads();
    const float* base = mask + ((size_t)b * Sn + qt * 128) * Sn + kt * 64;
    int r = t >> 1, c0 = (t & 1) * 32;
    const float* p = base + (size_t)r * Sn + c0;
    bool ok = true;
    for (int j = 0; j < 8; j++) {
      float4 vv = *(const float4*)(p + j * 4);
      ok = ok && (vv.x == 1.0f) && (vv.y == 1.0f) && (vv.z == 1.0f) && (vv.w == 1.0f);
    }
    if (!ok) atomicAnd(&ok_s, 0);
    __syncthreads();
    if (t == 0) flags[(b * 32 + kt) * 16 + qt] = ok_s;
  }
}

// ---------------------------------------------------------------------------
// GEMM core: 128x128 tile, BK=64, 4 waves; coalesced LDS-routed epilogues.
// AF32: A read from f32 via reg-staging (issue B gload_lds first, then f32
// loads 2-granules-at-a-time -> cvt -> ds_write_b128 to the same layout).
// mode 0: Q head-split bf16 * (0.125*log2e); 1: K head-split;
// mode 2: V -> vt[b][h][d][s]; mode 3: f32 flat out (+bias, nontemporal).
// ---------------------------------------------------------------------------
template <bool AF32>
__device__ __forceinline__ void gemm_body(const u16* __restrict__ A,
                                          const float* __restrict__ Af,
                                          const u16* __restrict__ BT,
                                          const float* __restrict__ bias,
                                          void* __restrict__ outp, int mode,
                                          int nt, int mt, char* sm) {
  const int K = 1024;
  int m0 = mt * 128, n0 = nt * 128;
  int tid = threadIdx.x, w = tid >> 6, l = tid & 63, l15 = l & 15, l4 = l >> 4;
  int wm = w >> 1, wn = w & 1;

  size_t goff_a[4], goff_b[4];
  int lbase[4];
  for (int i = 0; i < 4; i++) {
    int gi = (w * 4 + i) * 64 + l;
    int row = gi >> 3, g = gi & 7;
    int gx = g ^ (row & 7);
    goff_a[i] = (size_t)(m0 + row) * K + gx * 8;
    goff_b[i] = (size_t)(n0 + row) * K + gx * 8;
    lbase[i] = (w * 4 + i) * 1024;
  }

  f32x4 acc[4][4] = {};
  for (int t = 0; t < 16; t++) {
    int k0 = t * 64;
    if constexpr (AF32) {
      // B first (async), then A f32 -> bf16 reg-staged, 2 granules at a time
      for (int i = 0; i < 4; i++)
        GLDS16(BT + goff_b[i] + k0, sm + 16384 + lbase[i]);
#pragma unroll
      for (int ip = 0; ip < 2; ip++) {
        f32x4 a0[2], a1[2];
#pragma unroll
        for (int j = 0; j < 2; j++) {
          const float* src = Af + goff_a[ip * 2 + j] + k0;
          a0[j] = *(const f32x4*)src;
          a1[j] = *(const f32x4*)(src + 4);
        }
#pragma unroll
        for (int j = 0; j < 2; j++) {
          u16x8 pk;
          pk[0]=f2bf(a0[j][0]); pk[1]=f2bf(a0[j][1]); pk[2]=f2bf(a0[j][2]); pk[3]=f2bf(a0[j][3]);
          pk[4]=f2bf(a1[j][0]); pk[5]=f2bf(a1[j][1]); pk[6]=f2bf(a1[j][2]); pk[7]=f2bf(a1[j][3]);
          *(u16x8*)(sm + lbase[ip * 2 + j] + l * 16) = pk;
        }
      }
    } else {
      for (int i = 0; i < 4; i++) {
        GLDS16(A + goff_a[i] + k0, sm + lbase[i]);
        GLDS16(BT + goff_b[i] + k0, sm + 16384 + lbase[i]);
      }
    }
    __syncthreads();
#pragma unroll
    for (int kk = 0; kk < 2; kk++) {
      int kb = kk * 64 + l4 * 16;
      bf16x8 af[4], bf[4];
#pragma unroll
      for (int mi = 0; mi < 4; mi++) {
        int row = wm * 64 + mi * 16 + l15;
        af[mi] = *(const bf16x8*)(sm + row * 128 + (kb ^ ((row & 7) << 4)));
      }
#pragma unroll
      for (int nj = 0; nj < 4; nj++) {
        int row = wn * 64 + nj * 16 + l15;
        bf[nj] = *(const bf16x8*)(sm + 16384 + row * 128 + (kb ^ ((row & 7) << 4)));
      }
#pragma unroll
      for (int mi = 0; mi < 4; mi++)
#pragma unroll
        for (int nj = 0; nj < 4; nj++)
          acc[mi][nj] = __builtin_amdgcn_mfma_f32_16x16x32_bf16(af[mi], bf[nj], acc[mi][nj], 0, 0, 0);
    }
    __syncthreads();
  }

  if (mode == 3) {
    float* out = (float*)outp;
#pragma unroll
    for (int mi = 0; mi < 4; mi++)
#pragma unroll
      for (int nj = 0; nj < 4; nj++)
#pragma unroll
        for (int r = 0; r < 4; r++) {
          int mg = m0 + wm * 64 + mi * 16 + l4 * 4 + r;
          int ng = n0 + wn * 64 + nj * 16 + l15;
          __builtin_nontemporal_store(acc[mi][nj][r] + bias[ng],
                                      out + (size_t)mg * 1024 + ng);
        }
  } else if (mode == 2) {
    u16* vt = (u16*)outp;
#pragma unroll
    for (int mi = 0; mi < 4; mi++)
#pragma unroll
      for (int nj = 0; nj < 4; nj++) {
        int col = wn * 64 + nj * 16 + l15;
        int rowb = wm * 64 + mi * 16 + l4 * 4;
        float bs = bias[n0 + col];
        u16x4 pk;
#pragma unroll
        for (int r = 0; r < 4; r++) pk[r] = f2bf(acc[mi][nj][r] + bs);
        *(u16x4*)(sm + col * 256 + (((rowb >> 3) * 16) ^ ((col & 7) << 4)) + (rowb & 7) * 2) = pk;
      }
    __syncthreads();
#pragma unroll
    for (int pass = 0; pass < 8; pass++) {
      int idx = pass * 256 + tid;
      int g = idx & 15, col = idx >> 4;
      i32x4 v = *(const i32x4*)(sm + col * 256 + ((g * 16) ^ ((col & 7) << 4)));
      int ng = n0 + col, h = ng >> 6, d = ng & 63;
      int mgb = m0 + g * 8, b = mgb >> 11, s = mgb & 2047;
      *(i32x4*)(vt + ((size_t)(b * Hn + h) * DHn + d) * Sn + s) = v;
    }
  } else {
    u16* oh = (u16*)outp;
    float sc = (mode == 0) ? 0.18033688f : 1.0f;   // 0.125 * log2(e)
#pragma unroll
    for (int mi = 0; mi < 4; mi++)
#pragma unroll
      for (int nj = 0; nj < 4; nj++) {
        int col = wn * 64 + nj * 16 + l15;
        float bs = bias[n0 + col];
#pragma unroll
        for (int r = 0; r < 4; r++) {
          int row = wm * 64 + mi * 16 + l4 * 4 + r;
          *(u16*)(sm + row * 256 + (((col >> 3) * 16) ^ ((row & 7) << 4)) + (col & 7) * 2) =
              f2bf((acc[mi][nj][r] + bs) * sc);
        }
      }
    __syncthreads();
#pragma unroll
    for (int pass = 0; pass < 8; pass++) {
      int idx = pass * 256 + tid;
      int g = idx & 7, half = (idx >> 3) & 1, row = idx >> 4;
      i32x4 v = *(const i32x4*)(sm + row * 256 + (((half * 8 + g) * 16) ^ ((row & 7) << 4)));
      int hg = (n0 >> 6) + half;
      int mg = m0 + row, b = mg >> 11, s = mg & 2047;
      *(i32x4*)(oh + ((size_t)(b * Hn + hg) * Sn + s) * DHn + g * 8) = v;
    }
  }
}

__global__ __launch_bounds__(256) void gemmO_k(const u16* __restrict__ A,
                                               const u16* __restrict__ BT,
                                               const float* __restrict__ bias,
                                               float* __restrict__ outp) {
  __shared__ __align__(16) char sm[32768];
  int hw = blockIdx.x;
  int lg = (hw & 7) * 64 + (hw >> 3);
  int nt = lg & 7, mt = lg >> 3;
  gemm_body<false>(A, nullptr, BT, bias, (void*)outp, 3, nt, mt, sm);
}

// fused QKV projection from f32 inputs, 1D grid 1536, XCD-chunked (192)
__global__ __launch_bounds__(256) void gemm3_k(const float* __restrict__ qf,
                                               const float* __restrict__ kf,
                                               const float* __restrict__ vf,
                                               const u16* __restrict__ BTb,
                                               const float* __restrict__ b0,
                                               const float* __restrict__ b1,
                                               const float* __restrict__ b2,
                                               u16* __restrict__ outb) {
  __shared__ __align__(16) char sm[32768];
  int hw = blockIdx.x;
  int lg = (hw & 7) * 192 + (hw >> 3);
  int z = lg >> 9, r = lg & 511;
  int nt = r & 7, mt = r >> 3;
  const float* Af = z == 0 ? qf : z == 1 ? kf : vf;
  const u16* BT = BTb + (size_t)z * 1048576;
  const float* bias = z == 0 ? b0 : z == 1 ? b1 : b2;
  u16* out = outb + (size_t)z * 8388608;
  gemm_body<true>(nullptr, Af, BT, bias, (void*)out, z, nt, mt, sm);
}

// ---------------------------------------------------------------------------
// Merged attention (v12, unchanged). 1D grid 1024, XCD-chunked. 4 waves, 48KB.
// Phase A: c = log2(sum exp2(s')), KBLK=128, K dbuf in [0,32K).
// Phase B: KBLK=64, K/V dbuf, wave-private P; attn stored from the bf16 P
// tile in LDS, transposed: each instr = 4 rows x 256B contiguous (NT).
// LDS: K0 8K | K1 8K | V0 8K | V1 8K | P 16K = 48KB.
// ---------------------------------------------------------------------------
#define K0_OFF 0
#define K1_OFF 8192
#define V0_OFF 16384
#define V1_OFF 24576
#define P_OFF  32768

__global__ __launch_bounds__(256) void attn_k(
    const u16* __restrict__ qh, const u16* __restrict__ kh,
    const u16* __restrict__ vt, const float* __restrict__ mask,
    const int* __restrict__ flags, float* __restrict__ attn,
    u16* __restrict__ ctxc) {
  __shared__ __align__(16) char sm[49152];
  int hw = blockIdx.x;
  int lg = (hw & 7) * 128 + (hw >> 3);
  int qt = lg & 15, h = (lg >> 4) & 15, b = lg >> 8;
  int bh = b * Hn + h;
  int tid = threadIdx.x, w = tid >> 6, l = tid & 63, l15 = l & 15, l4 = l >> 4;

  const u16* Qg = qh + ((size_t)bh * Sn + qt * 128) * DHn;
  const u16* Kg = kh + (size_t)bh * Sn * DHn;
  const u16* Vg = vt + (size_t)bh * DHn * Sn;
  const float* Mg = mask + (size_t)b * Sn * Sn + (size_t)(qt * 128) * Sn;

  u32 fl = (u32)__ballot(l < 32 && flags[(b * 32 + l) * 16 + qt] != 0);

  int srowA[4], sgxA[4], sdstA[4];
  for (int i = 0; i < 4; i++) {
    int gid = i * 256 + tid, row = gid >> 3, g = gid & 7;
    srowA[i] = row; sgxA[i] = (g ^ (row & 7)) * 8; sdstA[i] = gid * 16;
  }
#define STAGE_KA(t, buf)                                                       \
  for (int i = 0; i < 4; i++)                                                  \
    GLDS16(Kg + (size_t)((t) * 128 + srowA[i]) * DHn + sgxA[i], sm + (buf) + sdstA[i]);
#define STAGE_K(t, buf)                                                        \
  for (int i = 0; i < 2; i++)                                                  \
    GLDS16(Kg + (size_t)((t) * 64 + srowA[i]) * DHn + sgxA[i], sm + (buf) + sdstA[i]);
#define STAGE_V(t, buf)                                                        \
  for (int i = 0; i < 2; i++)                                                  \
    GLDS16(Vg + (size_t)srowA[i] * Sn + (t) * 64 + sgxA[i], sm + (buf) + sdstA[i]);

  bf16x8 qf[2][2];
#pragma unroll
  for (int ni = 0; ni < 2; ni++)
#pragma unroll
    for (int kk = 0; kk < 2; kk++)
      qf[ni][kk] = *(const bf16x8*)(Qg + (size_t)(w * 32 + ni * 16 + l15) * DHn + kk * 32 + l4 * 8);

  // ---------------- phase A: lsum (no max tracking) ----------------
  float lsum[2] = {0.f, 0.f};
  STAGE_KA(0, 0);
  for (int t = 0; t < 16; t++) {
    int kcur = (t & 1) ? 16384 : 0;
    __syncthreads();
    if (t < 15) { int knxt = (t & 1) ? 0 : 16384; STAGE_KA(t + 1, knxt); }
#pragma unroll
    for (int h2 = 0; h2 < 2; h2++) {
      int kt = t * 2 + h2;
      f32x4 s[4][2] = {};
#pragma unroll
      for (int kk = 0; kk < 2; kk++) {
        int kb = kk * 64 + l4 * 16;
        bf16x8 a[4];
#pragma unroll
        for (int mi = 0; mi < 4; mi++) {
          int row = h2 * 64 + mi * 16 + l15;
          a[mi] = *(const bf16x8*)(sm + kcur + row * 128 + (kb ^ ((row & 7) << 4)));
        }
#pragma unroll
        for (int mi = 0; mi < 4; mi++)
#pragma unroll
          for (int ni = 0; ni < 2; ni++)
            s[mi][ni] = __builtin_amdgcn_mfma_f32_16x16x32_bf16(a[mi], qf[ni][kk], s[mi][ni], 0, 0, 0);
      }
      if (!((fl >> kt) & 1)) {
#pragma unroll
        for (int ni = 0; ni < 2; ni++) {
          const float* mrow = Mg + (size_t)(w * 32 + ni * 16 + l15) * Sn + kt * 64;
#pragma unroll
          for (int mi = 0; mi < 4; mi++) {
            f32x4 mv = *(const f32x4*)(mrow + mi * 16 + l4 * 4);
#pragma unroll
            for (int r = 0; r < 4; r++)
              s[mi][ni][r] = s[mi][ni][r] * mv[r] + MASK_NEG * (1.f - mv[r]);
          }
        }
      }
#pragma unroll
      for (int ni = 0; ni < 2; ni++)
#pragma unroll
        for (int mi = 0; mi < 4; mi++)
#pragma unroll
          for (int r = 0; r < 4; r++) lsum[ni] += __builtin_exp2f(s[mi][ni][r]);
    }
  }
  float cv[2];
#pragma unroll
  for (int ni = 0; ni < 2; ni++) {
    lsum[ni] += __shfl_xor(lsum[ni], 16);
    lsum[ni] += __shfl_xor(lsum[ni], 32);
    cv[ni] = __builtin_log2f(lsum[ni]);
  }

  // ---------------- phase B: P pack + transposed stores + PV ----------------
  __syncthreads();
  f32x4 ctx[4][2] = {};
  STAGE_K(0, K0_OFF);
  STAGE_V(0, V0_OFF);
  for (int t = 0; t < 32; t++) {
    int kcur = (t & 1) ? K1_OFF : K0_OFF;
    int vcur = (t & 1) ? V1_OFF : V0_OFF;
    __syncthreads();
    if (t < 31) {
      int knxt = (t & 1) ? K0_OFF : K1_OFF;
      int vnxt = (t & 1) ? V0_OFF : V1_OFF;
      STAGE_K(t + 1, knxt);
      STAGE_V(t + 1, vnxt);
    }
    f32x4 s[4][2] = {};
#pragma unroll
    for (int kk = 0; kk < 2; kk++) {
      int kb = kk * 64 + l4 * 16;
      bf16x8 a[4];
#pragma unroll
      for (int mi = 0; mi < 4; mi++) {
        int row = mi * 16 + l15;
        a[mi] = *(const bf16x8*)(sm + kcur + row * 128 + (kb ^ ((row & 7) << 4)));
      }
#pragma unroll
      for (int mi = 0; mi < 4; mi++)
#pragma unroll
        for (int ni = 0; ni < 2; ni++)
          s[mi][ni] = __builtin_amdgcn_mfma_f32_16x16x32_bf16(a[mi], qf[ni][kk], s[mi][ni], 0, 0, 0);
    }
    if (!((fl >> t) & 1)) {
#pragma unroll
      for (int ni = 0; ni < 2; ni++) {
        const float* mrow = Mg + (size_t)(w * 32 + ni * 16 + l15) * Sn + t * 64;
#pragma unroll
        for (int mi = 0; mi < 4; mi++) {
          f32x4 mv = *(const f32x4*)(mrow + mi * 16 + l4 * 4);
#pragma unroll
          for (int r = 0; r < 4; r++)
            s[mi][ni][r] = s[mi][ni][r] * mv[r] + MASK_NEG * (1.f - mv[r]);
        }
      }
    }
#pragma unroll
    for (int ni = 0; ni < 2; ni++)
#pragma unroll
      for (int mi = 0; mi < 4; mi++)
#pragma unroll
        for (int r = 0; r < 4; r++) s[mi][ni][r] = __builtin_exp2f(s[mi][ni][r] - cv[ni]);
    // P -> LDS (bf16, wave-private rows)
#pragma unroll
    for (int ni = 0; ni < 2; ni++) {
      int q = w * 32 + ni * 16 + l15;
#pragma unroll
      for (int mi = 0; mi < 4; mi++) {
        u16x4 pk;
#pragma unroll
        for (int r = 0; r < 4; r++) pk[r] = f2bf(s[mi][ni][r]);
        int kb = mi * 32 + l4 * 8;
        *(u16x4*)(sm + P_OFF + q * 128 + (kb ^ ((q & 7) << 4))) = pk;
      }
    }
    // attn store from LDS, transposed: instr j = 4 rows x 256B contiguous
#pragma unroll
    for (int j = 0; j < 8; j++) {
      int q = w * 32 + j * 4 + l4;
      u16x4 pv = *(const u16x4*)(sm + P_OFF + q * 128 + ((l15 * 8) ^ ((q & 7) << 4)));
      f32x4 o;
#pragma unroll
      for (int r = 0; r < 4; r++) o[r] = bf2f(pv[r]);
      nt_store4(attn + ((size_t)bh * Sn + qt * 128 + q) * Sn + t * 64 + l15 * 4, o);
    }
    // PV: ctx^T += Vt x P^T
#pragma unroll
    for (int kk = 0; kk < 2; kk++) {
      int kb = kk * 64 + l4 * 16;
      bf16x8 av[4], bp[2];
#pragma unroll
      for (int mi = 0; mi < 4; mi++) {
        int row = mi * 16 + l15;
        av[mi] = *(const bf16x8*)(sm + vcur + row * 128 + (kb ^ ((row & 7) << 4)));
      }
#pragma unroll
      for (int ni = 0; ni < 2; ni++) {
        int q = w * 32 + ni * 16 + l15;
        bp[ni] = *(const bf16x8*)(sm + P_OFF + q * 128 + (kb ^ ((q & 7) << 4)));
      }
#pragma unroll
      for (int mi = 0; mi < 4; mi++)
#pragma unroll
        for (int ni = 0; ni < 2; ni++)
          ctx[mi][ni] = __builtin_amdgcn_mfma_f32_16x16x32_bf16(av[mi], bp[ni], ctx[mi][ni], 0, 0, 0);
    }
  }

  // ctx epilogue (already normalized): bf16 pack, LDS, coalesced store
#pragma unroll
  for (int ni = 0; ni < 2; ni++) {
    int q = w * 32 + ni * 16 + l15;
#pragma unroll
    for (int mi = 0; mi < 4; mi++) {
      u16x4 ck;
#pragma unroll
      for (int r = 0; r < 4; r++) ck[r] = f2bf(ctx[mi][ni][r]);
      int db = mi * 32 + l4 * 8;
      *(u16x4*)(sm + P_OFF + q * 128 + (db ^ ((q & 7) << 4))) = ck;
    }
  }
  __syncthreads();
  {
    int q = tid >> 1, hf = tid & 1;
    u16* dst = ctxc + ((size_t)b * Sn + qt * 128 + q) * Dn + h * DHn + hf * 32;
#pragma unroll
    for (int c4 = 0; c4 < 4; c4++) {
      int db = hf * 64 + c4 * 16;
      i32x4 v = *(const i32x4*)(sm + P_OFF + q * 128 + (db ^ ((q & 7) << 4)));
      *(i32x4*)(dst + c4 * 8) = v;
    }
  }
}

// ---------------------------------------------------------------------------
extern "C" void kernel_launch(void* const* d_in, const int* in_sizes, int n_in,
                              void* d_out, int out_size, void* d_ws, size_t ws_size,
                              hipStream_t stream) {
  const float* v_f  = (const float*)d_in[0];
  const float* k_f  = (const float*)d_in[1];
  const float* q_f  = (const float*)d_in[2];
  const float* mask = (const float*)d_in[3];
  const float* wq_w = (const float*)d_in[4];
  const float* wq_b = (const float*)d_in[5];
  const float* wk_w = (const float*)d_in[6];
  const float* wk_b = (const float*)d_in[7];
  const float* wv_w = (const float*)d_in[8];
  const float* wv_b = (const float*)d_in[9];
  const float* wo_w = (const float*)d_in[10];
  const float* wo_b = (const float*)d_in[11];

  char* ws = (char*)d_ws;
  u16*   wT   = (u16*)(ws + 50331648);      // wqT,wkT,wvT,woT (contig, 2MB ea)
  u16*   woT  = (u16*)(ws + 56623104);
  u16*   qhp  = (u16*)(ws + 58720256);      // Qh, Kh, Vt slabs (contig, 16MB ea)
  u16*   khp  = (u16*)(ws + 75497472);
  u16*   vtp  = (u16*)(ws + 92274688);
  u16*   ctxc = (u16*)(ws + 109051904);
  int*   flg  = (int*)(ws + 125829120);

  float* out  = (float*)d_out;
  float* attn = out + (size_t)Bn * Sn * Dn;

  prep_k<<<3072, 256, 0, stream>>>(mask, wq_w, wk_w, wv_w, wo_w, wT, flg);
  gemm3_k<<<1536, 256, 0, stream>>>(q_f, k_f, v_f, wT, wq_b, wk_b, wv_b, qhp);
  attn_k<<<1024, 256, 0, stream>>>(qhp, khp, vtp, mask, flg, attn, ctxc);
  gemmO_k<<<512, 256, 0, stream>>>(ctxc, woT, wo_b, out);
}

// Round 15
// 531.964 us; speedup vs baseline: 1.3369x; 1.0037x over previous
//
#include <hip/hip_runtime.h>

// ---------------------------------------------------------------------------
// CustomizedMultiHeadAttention: B=4 S=2048 D=1024 H=16 DH=64
// out [B,S,D] f32  +  attn_weights [B,H,S,S] f32, concat in d_out.
// v15: = v14 except attn LDS 48->40KB (P compressed to 8KB wave-private
//      slots, store+PV issued per-ni) -> 4 blocks/CU, no residency tail.
// ---------------------------------------------------------------------------

typedef unsigned short u16;
typedef unsigned int   u32;
typedef u16   u16x4  __attribute__((ext_vector_type(4)));
typedef u16   u16x8  __attribute__((ext_vector_type(8)));
typedef int   i32x4  __attribute__((ext_vector_type(4)));
typedef float f32x4  __attribute__((ext_vector_type(4)));
typedef __bf16 bf16x8 __attribute__((ext_vector_type(8)));

#define GLDS16(gp, lp)                                                         \
  __builtin_amdgcn_global_load_lds(                                            \
      (const __attribute__((address_space(1))) void*)(gp),                     \
      (__attribute__((address_space(3))) void*)(lp), 16, 0, 0)

__device__ __forceinline__ u16 f2bf(float x) {
  __bf16 h = (__bf16)x;
  union { __bf16 h; u16 u; } c; c.h = h; return c.u;
}
__device__ __forceinline__ float bf2f(u16 x) {
  union { u32 u; float f; } v; v.u = ((u32)x) << 16; return v.f;
}
__device__ __forceinline__ void nt_store4(float* p, f32x4 v) {
  __builtin_nontemporal_store(v, (f32x4*)p);
}

static const int Bn = 4, Sn = 2048, Dn = 1024, Hn = 16, DHn = 64;
#define MASK_NEG (-1442695.0f)   /* -1e6 * log2(e) */

// ---------------------------------------------------------------------------
// prep: blocks [0,1024) weight cast+T; [1024,3072) mask all-ones flags.
// ---------------------------------------------------------------------------
__global__ __launch_bounds__(256) void prep_k(
    const float* __restrict__ mask,
    const float* __restrict__ w0, const float* __restrict__ w1,
    const float* __restrict__ w2, const float* __restrict__ w3,
    u16* __restrict__ WTb, int* __restrict__ flags) {
  __shared__ __align__(16) u16 tile[64][72];
  __shared__ int ok_s;
  int bid = blockIdx.x, t = threadIdx.x;

  if (bid < 1024) {                       // ---- weight cast + transpose
    int i = bid;
    int z = i >> 8, rem = i & 255, bx = rem & 15, by = rem >> 4;
    const float* W = z == 0 ? w0 : z == 1 ? w1 : z == 2 ? w2 : w3;
    u16* WT = WTb + (size_t)z * 1048576;
    for (int rr = 0; rr < 4; rr++) {
      int r = rr * 16 + (t >> 4);
      int c = (t & 15) * 4;
      float4 vv = *(const float4*)(W + (size_t)(by * 64 + r) * 1024 + bx * 64 + c);
      tile[c + 0][r] = f2bf(vv.x); tile[c + 1][r] = f2bf(vv.y);
      tile[c + 2][r] = f2bf(vv.z); tile[c + 3][r] = f2bf(vv.w);
    }
    __syncthreads();
    for (int rr = 0; rr < 2; rr++) {
      int gid = rr * 256 + t;
      int r = gid >> 3, g = gid & 7;
      u16x8 vv = *(const u16x8*)&tile[r][g * 8];
      *(u16x8*)(WT + (size_t)(bx * 64 + r) * 1024 + by * 64 + g * 8) = vv;
    }
  } else {                                // ---- mask flags
    int i = bid - 1024;
    int qt = i & 15, kt = (i >> 4) & 31, b = i >> 9;
    if (t == 0) ok_s = 1;
    __syncthreads();
    const float* base = mask + ((size_t)b * Sn + qt * 128) * Sn + kt * 64;
    int r = t >> 1, c0 = (t & 1) * 32;
    const float* p = base + (size_t)r * Sn + c0;
    bool ok = true;
    for (int j = 0; j < 8; j++) {
      float4 vv = *(const float4*)(p + j * 4);
      ok = ok && (vv.x == 1.0f) && (vv.y == 1.0f) && (vv.z == 1.0f) && (vv.w == 1.0f);
    }
    if (!ok) atomicAnd(&ok_s, 0);
    __syncthreads();
    if (t == 0) flags[(b * 32 + kt) * 16 + qt] = ok_s;
  }
}

// ---------------------------------------------------------------------------
// GEMM core: 128x128 tile, BK=64, 4 waves; coalesced LDS-routed epilogues.
// AF32: A read from f32 via reg-staging.
// ---------------------------------------------------------------------------
template <bool AF32>
__device__ __forceinline__ void gemm_body(const u16* __restrict__ A,
                                          const float* __restrict__ Af,
                                          const u16* __restrict__ BT,
                                          const float* __restrict__ bias,
                                          void* __restrict__ outp, int mode,
                                          int nt, int mt, char* sm) {
  const int K = 1024;
  int m0 = mt * 128, n0 = nt * 128;
  int tid = threadIdx.x, w = tid >> 6, l = tid & 63, l15 = l & 15, l4 = l >> 4;
  int wm = w >> 1, wn = w & 1;

  size_t goff_a[4], goff_b[4];
  int lbase[4];
  for (int i = 0; i < 4; i++) {
    int gi = (w * 4 + i) * 64 + l;
    int row = gi >> 3, g = gi & 7;
    int gx = g ^ (row & 7);
    goff_a[i] = (size_t)(m0 + row) * K + gx * 8;
    goff_b[i] = (size_t)(n0 + row) * K + gx * 8;
    lbase[i] = (w * 4 + i) * 1024;
  }

  f32x4 acc[4][4] = {};
  for (int t = 0; t < 16; t++) {
    int k0 = t * 64;
    if constexpr (AF32) {
      for (int i = 0; i < 4; i++)
        GLDS16(BT + goff_b[i] + k0, sm + 16384 + lbase[i]);
#pragma unroll
      for (int ip = 0; ip < 2; ip++) {
        f32x4 a0[2], a1[2];
#pragma unroll
        for (int j = 0; j < 2; j++) {
          const float* src = Af + goff_a[ip * 2 + j] + k0;
          a0[j] = *(const f32x4*)src;
          a1[j] = *(const f32x4*)(src + 4);
        }
#pragma unroll
        for (int j = 0; j < 2; j++) {
          u16x8 pk;
          pk[0]=f2bf(a0[j][0]); pk[1]=f2bf(a0[j][1]); pk[2]=f2bf(a0[j][2]); pk[3]=f2bf(a0[j][3]);
          pk[4]=f2bf(a1[j][0]); pk[5]=f2bf(a1[j][1]); pk[6]=f2bf(a1[j][2]); pk[7]=f2bf(a1[j][3]);
          *(u16x8*)(sm + lbase[ip * 2 + j] + l * 16) = pk;
        }
      }
    } else {
      for (int i = 0; i < 4; i++) {
        GLDS16(A + goff_a[i] + k0, sm + lbase[i]);
        GLDS16(BT + goff_b[i] + k0, sm + 16384 + lbase[i]);
      }
    }
    __syncthreads();
#pragma unroll
    for (int kk = 0; kk < 2; kk++) {
      int kb = kk * 64 + l4 * 16;
      bf16x8 af[4], bf[4];
#pragma unroll
      for (int mi = 0; mi < 4; mi++) {
        int row = wm * 64 + mi * 16 + l15;
        af[mi] = *(const bf16x8*)(sm + row * 128 + (kb ^ ((row & 7) << 4)));
      }
#pragma unroll
      for (int nj = 0; nj < 4; nj++) {
        int row = wn * 64 + nj * 16 + l15;
        bf[nj] = *(const bf16x8*)(sm + 16384 + row * 128 + (kb ^ ((row & 7) << 4)));
      }
#pragma unroll
      for (int mi = 0; mi < 4; mi++)
#pragma unroll
        for (int nj = 0; nj < 4; nj++)
          acc[mi][nj] = __builtin_amdgcn_mfma_f32_16x16x32_bf16(af[mi], bf[nj], acc[mi][nj], 0, 0, 0);
    }
    __syncthreads();
  }

  if (mode == 3) {
    float* out = (float*)outp;
#pragma unroll
    for (int mi = 0; mi < 4; mi++)
#pragma unroll
      for (int nj = 0; nj < 4; nj++)
#pragma unroll
        for (int r = 0; r < 4; r++) {
          int mg = m0 + wm * 64 + mi * 16 + l4 * 4 + r;
          int ng = n0 + wn * 64 + nj * 16 + l15;
          __builtin_nontemporal_store(acc[mi][nj][r] + bias[ng],
                                      out + (size_t)mg * 1024 + ng);
        }
  } else if (mode == 2) {
    u16* vt = (u16*)outp;
#pragma unroll
    for (int mi = 0; mi < 4; mi++)
#pragma unroll
      for (int nj = 0; nj < 4; nj++) {
        int col = wn * 64 + nj * 16 + l15;
        int rowb = wm * 64 + mi * 16 + l4 * 4;
        float bs = bias[n0 + col];
        u16x4 pk;
#pragma unroll
        for (int r = 0; r < 4; r++) pk[r] = f2bf(acc[mi][nj][r] + bs);
        *(u16x4*)(sm + col * 256 + (((rowb >> 3) * 16) ^ ((col & 7) << 4)) + (rowb & 7) * 2) = pk;
      }
    __syncthreads();
#pragma unroll
    for (int pass = 0; pass < 8; pass++) {
      int idx = pass * 256 + tid;
      int g = idx & 15, col = idx >> 4;
      i32x4 v = *(const i32x4*)(sm + col * 256 + ((g * 16) ^ ((col & 7) << 4)));
      int ng = n0 + col, h = ng >> 6, d = ng & 63;
      int mgb = m0 + g * 8, b = mgb >> 11, s = mgb & 2047;
      *(i32x4*)(vt + ((size_t)(b * Hn + h) * DHn + d) * Sn + s) = v;
    }
  } else {
    u16* oh = (u16*)outp;
    float sc = (mode == 0) ? 0.18033688f : 1.0f;   // 0.125 * log2(e)
#pragma unroll
    for (int mi = 0; mi < 4; mi++)
#pragma unroll
      for (int nj = 0; nj < 4; nj++) {
        int col = wn * 64 + nj * 16 + l15;
        float bs = bias[n0 + col];
#pragma unroll
        for (int r = 0; r < 4; r++) {
          int row = wm * 64 + mi * 16 + l4 * 4 + r;
          *(u16*)(sm + row * 256 + (((col >> 3) * 16) ^ ((row & 7) << 4)) + (col & 7) * 2) =
              f2bf((acc[mi][nj][r] + bs) * sc);
        }
      }
    __syncthreads();
#pragma unroll
    for (int pass = 0; pass < 8; pass++) {
      int idx = pass * 256 + tid;
      int g = idx & 7, half = (idx >> 3) & 1, row = idx >> 4;
      i32x4 v = *(const i32x4*)(sm + row * 256 + (((half * 8 + g) * 16) ^ ((row & 7) << 4)));
      int hg = (n0 >> 6) + half;
      int mg = m0 + row, b = mg >> 11, s = mg & 2047;
      *(i32x4*)(oh + ((size_t)(b * Hn + hg) * Sn + s) * DHn + g * 8) = v;
    }
  }
}

__global__ __launch_bounds__(256) void gemmO_k(const u16* __restrict__ A,
                                               const u16* __restrict__ BT,
                                               const float* __restrict__ bias,
                                               float* __restrict__ outp) {
  __shared__ __align__(16) char sm[32768];
  int hw = blockIdx.x;
  int lg = (hw & 7) * 64 + (hw >> 3);
  int nt = lg & 7, mt = lg >> 3;
  gemm_body<false>(A, nullptr, BT, bias, (void*)outp, 3, nt, mt, sm);
}

__global__ __launch_bounds__(256) void gemm3_k(const float* __restrict__ qf,
                                               const float* __restrict__ kf,
                                               const float* __restrict__ vf,
                                               const u16* __restrict__ BTb,
                                               const float* __restrict__ b0,
                                               const float* __restrict__ b1,
                                               const float* __restrict__ b2,
                                               u16* __restrict__ outb) {
  __shared__ __align__(16) char sm[32768];
  int hw = blockIdx.x;
  int lg = (hw & 7) * 192 + (hw >> 3);
  int z = lg >> 9, r = lg & 511;
  int nt = r & 7, mt = r >> 3;
  const float* Af = z == 0 ? qf : z == 1 ? kf : vf;
  const u16* BT = BTb + (size_t)z * 1048576;
  const float* bias = z == 0 ? b0 : z == 1 ? b1 : b2;
  u16* out = outb + (size_t)z * 8388608;
  gemm_body<true>(nullptr, Af, BT, bias, (void*)out, z, nt, mt, sm);
}

// ---------------------------------------------------------------------------
// Merged attention. 1D grid 1024, XCD-chunked. 4 waves, 40KB LDS ->
// 4 blocks/CU (no tail). Phase A: c = log2(sum exp2(s')), KBLK=128.
// Phase B: KBLK=64, K/V dbuf; P compressed to 8KB wave-private 16-row slots,
// reused per-ni: pack -> transposed 256B-run NT store -> PV, ni=0 then ni=1.
// LDS: K0 8K | K1 8K | V0 8K | V1 8K | P 8K = 40KB.
// ---------------------------------------------------------------------------
#define K0_OFF 0
#define K1_OFF 8192
#define V0_OFF 16384
#define V1_OFF 24576
#define P_OFF  32768

__global__ __launch_bounds__(256) void attn_k(
    const u16* __restrict__ qh, const u16* __restrict__ kh,
    const u16* __restrict__ vt, const float* __restrict__ mask,
    const int* __restrict__ flags, float* __restrict__ attn,
    u16* __restrict__ ctxc) {
  __shared__ __align__(16) char sm[40960];
  int hw = blockIdx.x;
  int lg = (hw & 7) * 128 + (hw >> 3);
  int qt = lg & 15, h = (lg >> 4) & 15, b = lg >> 8;
  int bh = b * Hn + h;
  int tid = threadIdx.x, w = tid >> 6, l = tid & 63, l15 = l & 15, l4 = l >> 4;

  const u16* Qg = qh + ((size_t)bh * Sn + qt * 128) * DHn;
  const u16* Kg = kh + (size_t)bh * Sn * DHn;
  const u16* Vg = vt + (size_t)bh * DHn * Sn;
  const float* Mg = mask + (size_t)b * Sn * Sn + (size_t)(qt * 128) * Sn;

  u32 fl = (u32)__ballot(l < 32 && flags[(b * 32 + l) * 16 + qt] != 0);

  int srowA[4], sgxA[4], sdstA[4];
  for (int i = 0; i < 4; i++) {
    int gid = i * 256 + tid, row = gid >> 3, g = gid & 7;
    srowA[i] = row; sgxA[i] = (g ^ (row & 7)) * 8; sdstA[i] = gid * 16;
  }
#define STAGE_KA(t, buf)                                                       \
  for (int i = 0; i < 4; i++)                                                  \
    GLDS16(Kg + (size_t)((t) * 128 + srowA[i]) * DHn + sgxA[i], sm + (buf) + sdstA[i]);
#define STAGE_K(t, buf)                                                        \
  for (int i = 0; i < 2; i++)                                                  \
    GLDS16(Kg + (size_t)((t) * 64 + srowA[i]) * DHn + sgxA[i], sm + (buf) + sdstA[i]);
#define STAGE_V(t, buf)                                                        \
  for (int i = 0; i < 2; i++)                                                  \
    GLDS16(Vg + (size_t)srowA[i] * Sn + (t) * 64 + sgxA[i], sm + (buf) + sdstA[i]);

  bf16x8 qf[2][2];
#pragma unroll
  for (int ni = 0; ni < 2; ni++)
#pragma unroll
    for (int kk = 0; kk < 2; kk++)
      qf[ni][kk] = *(const bf16x8*)(Qg + (size_t)(w * 32 + ni * 16 + l15) * DHn + kk * 32 + l4 * 8);

  // ---------------- phase A: lsum (no max tracking) ----------------
  float lsum[2] = {0.f, 0.f};
  STAGE_KA(0, 0);
  for (int t = 0; t < 16; t++) {
    int kcur = (t & 1) ? 16384 : 0;
    __syncthreads();
    if (t < 15) { int knxt = (t & 1) ? 0 : 16384; STAGE_KA(t + 1, knxt); }
#pragma unroll
    for (int h2 = 0; h2 < 2; h2++) {
      int kt = t * 2 + h2;
      f32x4 s[4][2] = {};
#pragma unroll
      for (int kk = 0; kk < 2; kk++) {
        int kb = kk * 64 + l4 * 16;
        bf16x8 a[4];
#pragma unroll
        for (int mi = 0; mi < 4; mi++) {
          int row = h2 * 64 + mi * 16 + l15;
          a[mi] = *(const bf16x8*)(sm + kcur + row * 128 + (kb ^ ((row & 7) << 4)));
        }
#pragma unroll
        for (int mi = 0; mi < 4; mi++)
#pragma unroll
          for (int ni = 0; ni < 2; ni++)
            s[mi][ni] = __builtin_amdgcn_mfma_f32_16x16x32_bf16(a[mi], qf[ni][kk], s[mi][ni], 0, 0, 0);
      }
      if (!((fl >> kt) & 1)) {
#pragma unroll
        for (int ni = 0; ni < 2; ni++) {
          const float* mrow = Mg + (size_t)(w * 32 + ni * 16 + l15) * Sn + kt * 64;
#pragma unroll
          for (int mi = 0; mi < 4; mi++) {
            f32x4 mv = *(const f32x4*)(mrow + mi * 16 + l4 * 4);
#pragma unroll
            for (int r = 0; r < 4; r++)
              s[mi][ni][r] = s[mi][ni][r] * mv[r] + MASK_NEG * (1.f - mv[r]);
          }
        }
      }
#pragma unroll
      for (int ni = 0; ni < 2; ni++)
#pragma unroll
        for (int mi = 0; mi < 4; mi++)
#pragma unroll
          for (int r = 0; r < 4; r++) lsum[ni] += __builtin_exp2f(s[mi][ni][r]);
    }
  }
  float cv[2];
#pragma unroll
  for (int ni = 0; ni < 2; ni++) {
    lsum[ni] += __shfl_xor(lsum[ni], 16);
    lsum[ni] += __shfl_xor(lsum[ni], 32);
    cv[ni] = __builtin_log2f(lsum[ni]);
  }

  // ---------------- phase B: per-ni pack + store + PV ----------------
  __syncthreads();
  f32x4 ctx[4][2] = {};
  STAGE_K(0, K0_OFF);
  STAGE_V(0, V0_OFF);
  int slot = w * 16 + l15;                    // wave-private P slot (pack)
  for (int t = 0; t < 32; t++) {
    int kcur = (t & 1) ? K1_OFF : K0_OFF;
    int vcur = (t & 1) ? V1_OFF : V0_OFF;
    __syncthreads();
    if (t < 31) {
      int knxt = (t & 1) ? K0_OFF : K1_OFF;
      int vnxt = (t & 1) ? V0_OFF : V1_OFF;
      STAGE_K(t + 1, knxt);
      STAGE_V(t + 1, vnxt);
    }
    f32x4 s[4][2] = {};
#pragma unroll
    for (int kk = 0; kk < 2; kk++) {
      int kb = kk * 64 + l4 * 16;
      bf16x8 a[4];
#pragma unroll
      for (int mi = 0; mi < 4; mi++) {
        int row = mi * 16 + l15;
        a[mi] = *(const bf16x8*)(sm + kcur + row * 128 + (kb ^ ((row & 7) << 4)));
      }
#pragma unroll
      for (int mi = 0; mi < 4; mi++)
#pragma unroll
        for (int ni = 0; ni < 2; ni++)
          s[mi][ni] = __builtin_amdgcn_mfma_f32_16x16x32_bf16(a[mi], qf[ni][kk], s[mi][ni], 0, 0, 0);
    }
    if (!((fl >> t) & 1)) {
#pragma unroll
      for (int ni = 0; ni < 2; ni++) {
        const float* mrow = Mg + (size_t)(w * 32 + ni * 16 + l15) * Sn + t * 64;
#pragma unroll
        for (int mi = 0; mi < 4; mi++) {
          f32x4 mv = *(const f32x4*)(mrow + mi * 16 + l4 * 4);
#pragma unroll
          for (int r = 0; r < 4; r++)
            s[mi][ni][r] = s[mi][ni][r] * mv[r] + MASK_NEG * (1.f - mv[r]);
        }
      }
    }
#pragma unroll
    for (int ni = 0; ni < 2; ni++)
#pragma unroll
      for (int mi = 0; mi < 4; mi++)
#pragma unroll
        for (int r = 0; r < 4; r++) s[mi][ni][r] = __builtin_exp2f(s[mi][ni][r] - cv[ni]);
    // V fragments (shared by both ni)
    bf16x8 av[4][2];
#pragma unroll
    for (int kk = 0; kk < 2; kk++) {
      int kb = kk * 64 + l4 * 16;
#pragma unroll
      for (int mi = 0; mi < 4; mi++) {
        int row = mi * 16 + l15;
        av[mi][kk] = *(const bf16x8*)(sm + vcur + row * 128 + (kb ^ ((row & 7) << 4)));
      }
    }
    // per-ni: P-pack (16 wave-private slots) -> transposed NT store -> PV
#pragma unroll
    for (int ni = 0; ni < 2; ni++) {
#pragma unroll
      for (int mi = 0; mi < 4; mi++) {
        u16x4 pk;
#pragma unroll
        for (int r = 0; r < 4; r++) pk[r] = f2bf(s[mi][ni][r]);
        int kb = mi * 32 + l4 * 8;
        *(u16x4*)(sm + P_OFF + slot * 128 + (kb ^ ((slot & 7) << 4))) = pk;
      }
      // transposed store: instr j = 4 rows x 256B contiguous runs
#pragma unroll
      for (int j = 0; j < 4; j++) {
        int rs = j * 4 + l4;                   // row within this ni-halftile
        int q = w * 32 + ni * 16 + rs;
        int ps = w * 16 + rs;
        u16x4 pv = *(const u16x4*)(sm + P_OFF + ps * 128 + ((l15 * 8) ^ ((ps & 7) << 4)));
        f32x4 o;
#pragma unroll
        for (int r = 0; r < 4; r++) o[r] = bf2f(pv[r]);
        nt_store4(attn + ((size_t)bh * Sn + qt * 128 + q) * Sn + t * 64 + l15 * 4, o);
      }
      // PV for this ni
#pragma unroll
      for (int kk = 0; kk < 2; kk++) {
        int kb = kk * 64 + l4 * 16;
        bf16x8 bp = *(const bf16x8*)(sm + P_OFF + slot * 128 + (kb ^ ((slot & 7) << 4)));
#pragma unroll
        for (int mi = 0; mi < 4; mi++)
          ctx[mi][ni] = __builtin_amdgcn_mfma_f32_16x16x32_bf16(av[mi][kk], bp, ctx[mi][ni], 0, 0, 0);
      }
    }
  }

  // ctx epilogue: pack into (now-dead) K region [128 rows][128B], coalesced
  __syncthreads();
#pragma unroll
  for (int ni = 0; ni < 2; ni++) {
    int q = w * 32 + ni * 16 + l15;
#pragma unroll
    for (int mi = 0; mi < 4; mi++) {
      u16x4 ck;
#pragma unroll
      for (int r = 0; r < 4; r++) ck[r] = f2bf(ctx[mi][ni][r]);
      int db = mi * 32 + l4 * 8;
      *(u16x4*)(sm + q * 128 + (db ^ ((q & 7) << 4))) = ck;
    }
  }
  __syncthreads();
  {
    int q = tid >> 1, hf = tid & 1;
    u16* dst = ctxc + ((size_t)b * Sn + qt * 128 + q) * Dn + h * DHn + hf * 32;
#pragma unroll
    for (int c4 = 0; c4 < 4; c4++) {
      int db = hf * 64 + c4 * 16;
      i32x4 v = *(const i32x4*)(sm + q * 128 + (db ^ ((q & 7) << 4)));
      *(i32x4*)(dst + c4 * 8) = v;
    }
  }
}

// ---------------------------------------------------------------------------
extern "C" void kernel_launch(void* const* d_in, const int* in_sizes, int n_in,
                              void* d_out, int out_size, void* d_ws, size_t ws_size,
                              hipStream_t stream) {
  const float* v_f  = (const float*)d_in[0];
  const float* k_f  = (const float*)d_in[1];
  const float* q_f  = (const float*)d_in[2];
  const float* mask = (const float*)d_in[3];
  const float* wq_w = (const float*)d_in[4];
  const float* wq_b = (const float*)d_in[5];
  const float* wk_w = (const float*)d_in[6];
  const float* wk_b = (const float*)d_in[7];
  const float* wv_w = (const float*)d_in[8];
  const float* wv_b = (const float*)d_in[9];
  const float* wo_w = (const float*)d_in[10];
  const float* wo_b = (const float*)d_in[11];

  char* ws = (char*)d_ws;
  u16*   wT   = (u16*)(ws + 50331648);      // wqT,wkT,wvT,woT (contig, 2MB ea)
  u16*   woT  = (u16*)(ws + 56623104);
  u16*   qhp  = (u16*)(ws + 58720256);      // Qh, Kh, Vt slabs (contig, 16MB ea)
  u16*   khp  = (u16*)(ws + 75497472);
  u16*   vtp  = (u16*)(ws + 92274688);
  u16*   ctxc = (u16*)(ws + 109051904);
  int*   flg  = (int*)(ws + 125829120);

  float* out  = (float*)d_out;
  float* attn = out + (size_t)Bn * Sn * Dn;

  prep_k<<<3072, 256, 0, stream>>>(mask, wq_w, wk_w, wv_w, wo_w, wT, flg);
  gemm3_k<<<1536, 256, 0, stream>>>(q_f, k_f, v_f, wT, wq_b, wk_b, wv_b, qhp);
  attn_k<<<1024, 256, 0, stream>>>(qhp, khp, vtp, mask, flg, attn, ctxc);
  gemmO_k<<<512, 256, 0, stream>>>(ctxc, woT, wo_b, out);
}